// Round 10
// baseline (270.935 us; speedup 1.0000x reference)
//
#include <hip/hip_runtime.h>

// spike_seq: (T=1024, B=16384, 2) fp32, values EXACTLY 0.0/1.0.
// Outputs flat: spk_rec (T*B) then mem_rec (T*B), fp32.
//
// R0-R9 unifying law: every structure (ours and rocclr's fillBuffer) retires
// ~1 vmem wave-instruction per ~90 CU-cycles. Throughput = 256 CUs x
// bytes/instr / 90cyc. fillBuffer: 1KB/instr -> 6.7 TB/s. Our scans: 256B
// rows (64 neurons/CU) -> 2.5 TB/s regardless of pipelining/domains/rings.
// Fix: checkpoint+replay decouples the sequential scan from the I/O tiling
// so every kernel uses 16B/lane instructions on all 256 CUs:
//   K1  compress x -> 2 bits/sample (4MB ws), float4 reads, 1KB/instr.
//   K2a scan t<896 on compressed input, store 7 (mem,inh) checkpoints.
//   K2b 512 blocks (64 neuron-groups x 8 T-segments): replay 128 steps from
//       checkpoint (bit-identical: same op order, exact {0,1} inputs) and
//       store the 256-neuron x 128-row tile via LDS transpose: one
//       global_store_dwordx4 = one full 1KB row-slice.
#define T_LEN 1024
#define B_N   16384
#define NSEG  8
#define SEGT  (T_LEN / NSEG)       // 128
#define GN    256                  // neurons per K2b block
#define PH2   8                    // steps per K2b phase
#define NPH2  (SEGT / PH2)         // 16
#define CW_WORDS (B_N * (T_LEN / 16))  // 1,048,576 words = 4 MB

// ---------------------------------------------------------------------------
// K1: word (j,n) packs t=16j..16j+15 of neuron n: bit(2k)=x0, bit(2k+1)=x1.
// Thread handles neurons (2p, 2p+1): reads float4 (1KB/wave-instr contiguous).
__global__ __launch_bounds__(256) void k1_compress(
    const float* __restrict__ x, unsigned int* __restrict__ cw) {
  const int tid = blockIdx.x * 256 + threadIdx.x;   // 0..524287
  const int pn  = tid & (B_N / 2 - 1);              // float4 column
  const int j   = tid >> 13;                        // 0..63
  const float4* xp4 = (const float4*)x;
  unsigned int wA = 0, wB = 0;
#pragma unroll
  for (int k = 0; k < 16; ++k) {
    const float4 v = xp4[(size_t)(16 * j + k) * (B_N / 2) + pn];
    wA |= (v.x != 0.0f ? 1u : 0u) << (2 * k);
    wA |= (v.y != 0.0f ? 1u : 0u) << (2 * k + 1);
    wB |= (v.z != 0.0f ? 1u : 0u) << (2 * k);
    wB |= (v.w != 0.0f ? 1u : 0u) << (2 * k + 1);
  }
  ((uint2*)cw)[(size_t)j * (B_N / 2) + pn] = make_uint2(wA, wB);
}

// ---------------------------------------------------------------------------
// K2a: sequential scan t=0..895 (last segment needs no checkpoint), 1 thread
// per neuron. 4-word rolling prefetch (64 steps consume ~1000cy > HBM/LLC
// latency); only 7 tiny float2 stores total -> load waits never chain.
__global__ __launch_bounds__(64, 1) void k2a_checkpoint(
    const unsigned int* __restrict__ cw,
    const float* __restrict__ w_exc, const float* __restrict__ w_inh,
    float2* __restrict__ chk) {
#pragma clang fp contract(off)
  const int n = blockIdx.x * 64 + threadIdx.x;
  const float w0 = w_exc[0], w1 = w_exc[1], wi = w_inh[0];
  float mem = 0.0f, inh = 0.0f;
  unsigned int A = cw[n];
  unsigned int Bw = cw[(size_t)1 * B_N + n];
  unsigned int C = cw[(size_t)2 * B_N + n];
  unsigned int D = cw[(size_t)3 * B_N + n];

#define STEP16(W)                                                   \
  _Pragma("unroll") for (int k = 0; k < 16; ++k) {                  \
    const float x0 = (float)(((W) >> (2 * k)) & 1u);                \
    const float x1 = (float)(((W) >> (2 * k + 1)) & 1u);            \
    const float cur_exc = x0 * w0 + x1 * w1;  /* exact ref order */ \
    inh = 0.6f * inh + x0;                                          \
    const float cur = cur_exc + wi * inh;     /* wi=-1 exact */     \
    const float reset = (mem > 1.0f) ? 1.0f : 0.0f;                 \
    mem = 0.9f * mem + cur - reset;           /* reset*1.0==reset */\
  }

  for (int j = 0; j < 56; j += 4) {
    unsigned int nA = 0, nB = 0, nC = 0, nD = 0;
    if (j + 4 < 56) {
      nA = cw[(size_t)(j + 4) * B_N + n];
      nB = cw[(size_t)(j + 5) * B_N + n];
      nC = cw[(size_t)(j + 6) * B_N + n];
      nD = cw[(size_t)(j + 7) * B_N + n];
    }
    __builtin_amdgcn_sched_barrier(0);  // keep prefetch issued before consume
    STEP16(A) STEP16(Bw) STEP16(C) STEP16(D)
    if (((j + 4) & 7) == 0)  // after words 0..j+3 = t multiple of 128
      chk[(size_t)(((j + 4) >> 3) - 1) * B_N + n] = make_float2(mem, inh);
    A = nA; Bw = nB; C = nC; D = nD;
  }
#undef STEP16
}

// ---------------------------------------------------------------------------
// K2b: 512 blocks: seg = bx>>6 (consecutive blocks share a segment -> rows
// written together), g = bx&63. 6 waves: w0-3 compute (64 neurons each),
// w4 spk-storer, w5 mem-storer. Double-buffered LDS planes; raw s_barrier +
// lgkmcnt only (storers' global stores fire-and-forget in their own vmcnt
// domains; compute has zero vmem after its 2-scalar prologue + rolling word).
__shared__ __align__(16) float SPK[2][PH2][GN];   // 16 KiB
__shared__ __align__(16) float MEM[2][PH2][GN];   // 16 KiB

static __device__ __forceinline__ void block_barrier() {
  asm volatile("" ::: "memory");
  __builtin_amdgcn_s_barrier();
  asm volatile("" ::: "memory");
}

__global__ __launch_bounds__(384, 1) void FMFMNeuronInhib_34033320854098_kernel(
    const unsigned int* __restrict__ cw, const float2* __restrict__ chk,
    const float* __restrict__ w_exc, const float* __restrict__ w_inh,
    float* __restrict__ out) {
#pragma clang fp contract(off)
  const int lane = threadIdx.x & 63;
  const int wid  = threadIdx.x >> 6;      // 0-3 compute, 4 spk-st, 5 mem-st
  const int seg  = blockIdx.x >> 6;       // 0..7
  const int g    = blockIdx.x & 63;       // neuron group
  const int nb0  = g * GN;
  const int tseg = seg * SEGT;

  if (wid < 4) {
    // ---------------- compute ----------------
    const int nloc = wid * 64 + lane;     // 0..255
    const int n    = nb0 + nloc;
    const float w0 = w_exc[0], w1 = w_exc[1], wi = w_inh[0];
    float mem = 0.0f, inh = 0.0f;
    if (seg > 0) {
      const float2 c = chk[(size_t)(seg - 1) * B_N + n];
      mem = c.x; inh = c.y;
    }
    unsigned int wcur = cw[(size_t)(seg * 8) * B_N + n];
    for (int jl = 0; jl < 8; ++jl) {      // one word = 2 phases of 8 steps
      unsigned int wnext = 0u;
      if (jl < 7) wnext = cw[(size_t)(seg * 8 + jl + 1) * B_N + n];
#pragma unroll
      for (int half = 0; half < 2; ++half) {   // slot & bit-base are STATIC
#pragma unroll
        for (int u = 0; u < 8; ++u) {
          const int k = half * 8 + u;
          const float x0 = (float)((wcur >> (2 * k)) & 1u);
          const float x1 = (float)((wcur >> (2 * k + 1)) & 1u);
          // Exact reference op order; no FMA contraction.
          const float cur_exc = x0 * w0 + x1 * w1;
          inh = 0.6f * inh + x0;
          const float cur = cur_exc + wi * inh;
          const float reset = (mem > 1.0f) ? 1.0f : 0.0f;
          mem = 0.9f * mem + cur - reset;
          const float spk = (mem > 1.0f) ? 1.0f : 0.0f;
          SPK[half][u][nloc] = spk;       // lane-consecutive: conflict-free
          MEM[half][u][nloc] = mem;
        }
        asm volatile("s_waitcnt lgkmcnt(0)" ::: "memory");  // visible to storers
        block_barrier();                  // barrier #(2*jl+half)
      }
      wcur = wnext;
    }
  } else {
    // ---------------- storers ----------------
    float* gout = (wid == 4) ? out : out + (size_t)T_LEN * B_N;
    const float* plane = (wid == 4) ? &SPK[0][0][0] : &MEM[0][0][0];
    const int n0 = lane * 4;              // one dwordx4 = one full 1KB row
    auto drain = [&](int p) {
      const int slot = p & 1;
      const int t0   = tseg + p * PH2;
#pragma unroll
      for (int r = 0; r < PH2; ++r) {
        const float4 v =
            *(const float4*)(plane + ((size_t)slot * PH2 + r) * GN + n0);
        *(float4*)&gout[(size_t)(t0 + r) * B_N + nb0 + n0] = v;
      }
      // ds_reads retired (data consumed into store issue); stores drain in
      // this wave's own vmcnt domain — nothing ever waits on them.
      asm volatile("s_waitcnt lgkmcnt(0)" ::: "memory");
    };
    for (int p = 0; p < NPH2; ++p) {
      if (p >= 1) drain(p - 1);           // reads slot (p-1)&1 vs compute p&1
      block_barrier();                    // barrier #p (matches compute)
    }
    drain(NPH2 - 1);                      // ordered by the last barrier
  }
}

extern "C" void kernel_launch(void* const* d_in, const int* in_sizes, int n_in,
                              void* d_out, int out_size, void* d_ws, size_t ws_size,
                              hipStream_t stream) {
  const float* x     = (const float*)d_in[0];
  const float* w_exc = (const float*)d_in[1];
  const float* w_inh = (const float*)d_in[2];
  float* out = (float*)d_out;
  unsigned int* cw = (unsigned int*)d_ws;                       // 4 MB
  float2* chk = (float2*)((char*)d_ws + (size_t)CW_WORDS * 4);  // 896 KB

  hipLaunchKernelGGL(k1_compress, dim3(CW_WORDS / 2 / 256), dim3(256), 0,
                     stream, x, cw);
  hipLaunchKernelGGL(k2a_checkpoint, dim3(B_N / 64), dim3(64), 0, stream,
                     cw, w_exc, w_inh, chk);
  hipLaunchKernelGGL(FMFMNeuronInhib_34033320854098_kernel,
                     dim3(NSEG * (B_N / GN)), dim3(384), 0, stream,
                     cw, chk, w_exc, w_inh, out);
}

// Round 11
// 270.318 us; speedup vs baseline: 1.0023x; 1.0023x over previous
//
#include <hip/hip_runtime.h>

// spike_seq: (T=1024, B=16384, 2) fp32, values EXACTLY 0.0/1.0.
// Outputs flat: spk_rec (T*B) then mem_rec (T*B), fp32.
//
// Split design (R9/R10 lineage), R11 revision:
//   K1  compress x -> 2 bits/sample (4 MB ws). Fat float4 reads, ~21 us.
//   K2a sequential scan t<896 on compressed input (1 wave/CU VALU chain),
//       stores 7 (mem,inh) checkpoints. ~6-9 us.
//   K2b' replay: R8's PROVEN 11 B/cyc/CU structure (4 compute waves,
//       DIRECT global stores, barrier-per-word wave alignment, no LDS, no
//       storer waves) on a 512-block grid = 8 segs x 64 groups x 256
//       neurons, 2 blocks/CU, all 256 CUs. R10's K2b (LDS-transpose +
//       storer waves + 16-barrier lockstep) is the suspected ~80 us pig by
//       elimination; R8 measured this simpler shape at fillBuffer's per-CU
//       rate, so reuse it verbatim.
#define T_LEN 1024
#define B_N   16384
#define NSEG  8
#define SEGT  (T_LEN / NSEG)           // 128
#define GN    256                      // neurons per replay block
#define CW_WORDS (B_N * (T_LEN / 16))  // 1,048,576 words = 4 MB

// ---------------------------------------------------------------------------
// K1: word (j,n) packs t=16j..16j+15 of neuron n: bit(2k)=x0, bit(2k+1)=x1.
// Thread handles neurons (2p, 2p+1): float4 reads = 1KB/wave-instr contiguous.
__global__ __launch_bounds__(256) void k1_compress(
    const float* __restrict__ x, unsigned int* __restrict__ cw) {
  const int tid = blockIdx.x * 256 + threadIdx.x;   // 0..524287
  const int pn  = tid & (B_N / 2 - 1);              // float4 column
  const int j   = tid >> 13;                        // 0..63
  const float4* xp4 = (const float4*)x;
  unsigned int wA = 0, wB = 0;
#pragma unroll
  for (int k = 0; k < 16; ++k) {
    const float4 v = xp4[(size_t)(16 * j + k) * (B_N / 2) + pn];
    wA |= (v.x != 0.0f ? 1u : 0u) << (2 * k);
    wA |= (v.y != 0.0f ? 1u : 0u) << (2 * k + 1);
    wB |= (v.z != 0.0f ? 1u : 0u) << (2 * k);
    wB |= (v.w != 0.0f ? 1u : 0u) << (2 * k + 1);
  }
  ((uint2*)cw)[(size_t)j * (B_N / 2) + pn] = make_uint2(wA, wB);
}

// ---------------------------------------------------------------------------
// K2a: sequential scan t=0..895, 1 thread/neuron, 256 blocks = 1 wave/CU.
// 4-word rolling prefetch; 7 tiny float2 checkpoint stores total.
__global__ __launch_bounds__(64, 1) void k2a_checkpoint(
    const unsigned int* __restrict__ cw,
    const float* __restrict__ w_exc, const float* __restrict__ w_inh,
    float2* __restrict__ chk) {
#pragma clang fp contract(off)
  const int n = blockIdx.x * 64 + threadIdx.x;
  const float w0 = w_exc[0], w1 = w_exc[1], wi = w_inh[0];
  float mem = 0.0f, inh = 0.0f;
  unsigned int A = cw[n];
  unsigned int Bw = cw[(size_t)1 * B_N + n];
  unsigned int C = cw[(size_t)2 * B_N + n];
  unsigned int D = cw[(size_t)3 * B_N + n];

#define STEP16(W)                                                   \
  _Pragma("unroll") for (int k = 0; k < 16; ++k) {                  \
    const float x0 = (float)(((W) >> (2 * k)) & 1u);                \
    const float x1 = (float)(((W) >> (2 * k + 1)) & 1u);            \
    const float cur_exc = x0 * w0 + x1 * w1;  /* exact ref order */ \
    inh = 0.6f * inh + x0;                                          \
    const float cur = cur_exc + wi * inh;     /* wi=-1 exact */     \
    const float reset = (mem > 1.0f) ? 1.0f : 0.0f;                 \
    mem = 0.9f * mem + cur - reset;           /* reset*1.0==reset */\
  }

  for (int j = 0; j < 56; j += 4) {
    unsigned int nA = 0, nB = 0, nC = 0, nD = 0;
    if (j + 4 < 56) {
      nA = cw[(size_t)(j + 4) * B_N + n];
      nB = cw[(size_t)(j + 5) * B_N + n];
      nC = cw[(size_t)(j + 6) * B_N + n];
      nD = cw[(size_t)(j + 7) * B_N + n];
    }
    __builtin_amdgcn_sched_barrier(0);  // prefetch issued before consume
    STEP16(A) STEP16(Bw) STEP16(C) STEP16(D)
    if (((j + 4) & 7) == 0)  // state after t = 128*c - 1
      chk[(size_t)(((j + 4) >> 3) - 1) * B_N + n] = make_float2(mem, inh);
    A = nA; Bw = nB; C = nC; D = nD;
  }
#undef STEP16
}

// ---------------------------------------------------------------------------
// K2b': replay + store, R8's measured-good shape. Block (seg,g): 256 threads
// = 4 waves own neurons [g*256, g*256+256). Per thread: checkpoint float2 +
// 8 cw words (all loads in the prologue -> the store-only main loop never
// has a load-wait chained behind store acks), then 128 fully-unrolled steps
// with direct dword stores (wave = 256B contiguous; the block's 4 waves,
// re-aligned by a barrier every 16 steps, cluster each row's 1KB slice into
// one page burst — the exact pattern R8 measured at 11 B/cyc/CU).
__global__ __launch_bounds__(256, 2) void FMFMNeuronInhib_34033320854098_kernel(
    const unsigned int* __restrict__ cw, const float2* __restrict__ chk,
    const float* __restrict__ w_exc, const float* __restrict__ w_inh,
    float* __restrict__ out) {
#pragma clang fp contract(off)
  const int seg = blockIdx.x >> 6;          // 0..7
  const int g   = blockIdx.x & 63;          // neuron group
  const int n   = g * GN + threadIdx.x;     // this thread's neuron

  float* __restrict__ spk_out = out;
  float* __restrict__ mem_out = out + (size_t)T_LEN * B_N;

  const float w0 = w_exc[0], w1 = w_exc[1], wi = w_inh[0];
  float mem = 0.0f, inh = 0.0f;
  if (seg > 0) {
    const float2 c = chk[(size_t)(seg - 1) * B_N + n];
    mem = c.x;
    inh = c.y;
  }
  unsigned int w[8];
#pragma unroll
  for (int j = 0; j < 8; ++j) w[j] = cw[(size_t)(seg * 8 + j) * B_N + n];

#pragma unroll
  for (int j = 0; j < 8; ++j) {             // static indexing: w[j] stays in
#pragma unroll                              // VGPRs (rule: no runtime idx)
    for (int k = 0; k < 16; ++k) {
      const int t = seg * SEGT + j * 16 + k;
      const float x0 = (float)((w[j] >> (2 * k)) & 1u);      // exact 0.0/1.0
      const float x1 = (float)((w[j] >> (2 * k + 1)) & 1u);
      // Exact reference op order; no FMA contraction (1 ulp flips a spike).
      const float cur_exc = x0 * w0 + x1 * w1;   // x @ w_exc^T
      inh = 0.6f * inh + x0;                     // inh decay + feed
      const float cur = cur_exc + wi * inh;      // wi = -1.0 exact
      // (mem-1>0) == (mem>1) exactly; reset*1.0f == reset.
      const float reset = (mem > 1.0f) ? 1.0f : 0.0f;
      mem = 0.9f * mem + cur - reset;
      const float spk = (mem > 1.0f) ? 1.0f : 0.0f;
      const size_t idx = (size_t)t * B_N + n;
      spk_out[idx] = spk;   // fire-and-forget; this wave's vmcnt domain has
      mem_out[idx] = mem;   // no loads after the prologue -> nothing waits
    }
    // Re-align the block's 4 waves so their 256B slices of each row land as
    // one 1KB page burst (R8's clustering). No memory drain: s_barrier does
    // not wait on vmcnt, outstanding stores keep flowing.
    __builtin_amdgcn_s_barrier();
  }
}

extern "C" void kernel_launch(void* const* d_in, const int* in_sizes, int n_in,
                              void* d_out, int out_size, void* d_ws, size_t ws_size,
                              hipStream_t stream) {
  const float* x     = (const float*)d_in[0];
  const float* w_exc = (const float*)d_in[1];
  const float* w_inh = (const float*)d_in[2];
  float* out = (float*)d_out;
  unsigned int* cw = (unsigned int*)d_ws;                       // 4 MB
  float2* chk = (float2*)((char*)d_ws + (size_t)CW_WORDS * 4);  // 896 KB

  hipLaunchKernelGGL(k1_compress, dim3(CW_WORDS / 2 / 256), dim3(256), 0,
                     stream, x, cw);
  hipLaunchKernelGGL(k2a_checkpoint, dim3(B_N / 64), dim3(64), 0, stream,
                     cw, w_exc, w_inh, chk);
  hipLaunchKernelGGL(FMFMNeuronInhib_34033320854098_kernel,
                     dim3(NSEG * (B_N / GN)), dim3(GN), 0, stream,
                     cw, chk, w_exc, w_inh, out);
}